// Round 1
// baseline (715.195 us; speedup 1.0000x reference)
//
#include <hip/hip_runtime.h>
#include <stdint.h>

// Problem constants: B=32, N=1024, IN=64, ATTN=128, OUT=64, H=4, dh=32
typedef __attribute__((ext_vector_type(4))) float f32x4;
typedef __attribute__((ext_vector_type(4))) unsigned int u32x4;
typedef __attribute__((ext_vector_type(2))) unsigned int u32x2;
typedef __attribute__((ext_vector_type(8))) short bf16x8;

__device__ __forceinline__ unsigned short f2bf(float f) {
    union { float f; unsigned int u; } c; c.f = f;
    unsigned int u = c.u;
    unsigned int r = (u + 0x7FFFu + ((u >> 16) & 1u)) >> 16;  // RNE
    return (unsigned short)r;
}
__device__ __forceinline__ float bf2f(unsigned short h) {
    union { unsigned int u; float f; } c; c.u = ((unsigned int)h) << 16;
    return c.f;
}
__device__ __forceinline__ float tanh_fast(float x) {
    float ax = fminf(fabsf(x), 12.0f);
    float e  = __expf(2.0f * ax);
    float t  = 1.0f - 2.0f * __builtin_amdgcn_rcpf(e + 1.0f);
    return copysignf(t, x);
}

// ---------------- kernel A: degrees d = rsqrt(max(rowsum(adj'),1)) -------------
__global__ __launch_bounds__(256) void k_deg(const float* __restrict__ adj,
                                             float* __restrict__ dvec) {
    int wid = threadIdx.x >> 6, l = threadIdx.x & 63;
    int row = blockIdx.x * 4 + wid;          // 0..32767
    int b = row >> 10, i = row & 1023;
    const float* rp = adj + ((size_t)b << 20) + ((size_t)i << 10);
    float s = 0.f;
#pragma unroll
    for (int it = 0; it < 4; ++it) {
        f32x4 v = *(const f32x4*)(rp + it * 256 + l * 4);
        s += v.x + v.y + v.z + v.w;
    }
#pragma unroll
    for (int m = 32; m >= 1; m >>= 1) s += __shfl_xor(s, m);
    if (l == 0) {
        float diag = rp[i];
        float S = s - diag + 1.0f;     // diagonal replaced by 1
        S = fmaxf(S, 1.0f);
        dvec[(b << 10) + i] = 1.0f / sqrtf(S);
    }
}

// ---------------- kernel B: h'T[b][c][j] = d_j * (x[j,:] @ W[:,c]) (bf16) ------
__global__ __launch_bounds__(256) void k_xw(const float* __restrict__ x,
                                            const float* __restrict__ Wq,
                                            const float* __restrict__ Wk,
                                            const float* __restrict__ Wv,
                                            const float* __restrict__ dvec,
                                            unsigned short* __restrict__ hT) {
    int wid = threadIdx.x >> 6, l = threadIdx.x & 63;
    int b  = blockIdx.x >> 4;
    int j0 = (blockIdx.x & 15) << 6;
    int j  = j0 + l;
    const float* xrow = x + ((size_t)((b << 10) + j)) * 64;
    f32x4 xq[16];
#pragma unroll
    for (int k4 = 0; k4 < 16; ++k4) xq[k4] = *(const f32x4*)(xrow + k4 * 4);
    float dj = dvec[(b << 10) + j];
#pragma unroll 1
    for (int cc = 0; cc < 20; ++cc) {
        int c = wid * 80 + cc * 4;           // [0,320), 4-col block, never straddles 128/256
        const float* Wp; int wc, wst;
        if (c < 128)      { Wp = Wq; wc = c;       wst = 128; }
        else if (c < 256) { Wp = Wk; wc = c - 128; wst = 128; }
        else              { Wp = Wv; wc = c - 256; wst = 64;  }
        f32x4 a = {0.f, 0.f, 0.f, 0.f};
#pragma unroll
        for (int k = 0; k < 64; ++k) {
            f32x4 w = *(const f32x4*)(Wp + k * wst + wc);
            a += xq[k >> 2][k & 3] * w;
        }
        a *= dj;
        size_t ob = ((size_t)b * 320 + c) * 1024 + j;
        hT[ob]        = f2bf(a.x);
        hT[ob + 1024] = f2bf(a.y);
        hT[ob + 2048] = f2bf(a.z);
        hT[ob + 3072] = f2bf(a.w);
    }
}

// ---------------- kernel C: G = adj' @ h' ; Q,K -> bf16 hi/lo ws, V -> d_out ---
#define APAD 72   // LDS row stride (bf16 elems): 144B -> 2-way bank alias only
__global__ __launch_bounds__(256) void k_gcn(const float* __restrict__ adj,
                                             const unsigned short* __restrict__ hT,
                                             const float* __restrict__ dvec,
                                             const float* __restrict__ bq,
                                             const float* __restrict__ bk,
                                             const float* __restrict__ bv,
                                             unsigned short* __restrict__ QKhi,
                                             unsigned short* __restrict__ QKlo,
                                             float* __restrict__ outV) {
    __shared__ unsigned short Al[128][APAD];
    __shared__ unsigned short Bl[64][APAD];
    // XCD swizzle: batch b pinned to XCD b&7; 5 N-tiles consecutive on that XCD
    int bid = blockIdx.x;
    int xcd = bid & 7, t2 = bid >> 3;
    int bg = t2 / 40, blk = t2 % 40;
    int b  = (bg << 3) + xcd;
    int mt = blk / 5, nt = blk % 5;
    int i0 = mt << 7, c0 = nt << 6;
    int tid = threadIdx.x;
    int wid = tid >> 6, l = tid & 63;
    int wm = wid >> 1, wn = wid & 1;
    int lr = l & 15, lg = l >> 4;

    f32x4 acc[4][2];
#pragma unroll
    for (int mi = 0; mi < 4; ++mi)
#pragma unroll
        for (int ni = 0; ni < 2; ++ni) acc[mi][ni] = (f32x4){0.f, 0.f, 0.f, 0.f};

    const float* adjB = adj + ((size_t)b << 20);
    const unsigned short* hTB = hT + (size_t)b * 320 * 1024;
    int ar0 = tid >> 4;            // 0..15
    int ac4 = (tid & 15) << 2;     // 0..60

    for (int kt = 0; kt < 16; ++kt) {
        int j0 = kt << 6;
        __syncthreads();
        // stage A: adj[i0..+127][j0..+63] f32 -> bf16, diag patch
#pragma unroll
        for (int rr = 0; rr < 8; ++rr) {
            int row = ar0 + (rr << 4);
            int gi  = i0 + row;
            f32x4 v = *(const f32x4*)(adjB + ((size_t)gi << 10) + j0 + ac4);
            int gj = j0 + ac4;
            if (gj + 0 == gi) v.x = 1.0f;
            if (gj + 1 == gi) v.y = 1.0f;
            if (gj + 2 == gi) v.z = 1.0f;
            if (gj + 3 == gi) v.w = 1.0f;
            u32x2 pk;
            pk.x = (unsigned)f2bf(v.x) | ((unsigned)f2bf(v.y) << 16);
            pk.y = (unsigned)f2bf(v.z) | ((unsigned)f2bf(v.w) << 16);
            *(u32x2*)&Al[row][ac4] = pk;
        }
        // stage B: h'T rows c0..+63, cols j0..+63 (already bf16)
#pragma unroll
        for (int rep = 0; rep < 2; ++rep) {
            int idx = (rep << 8) + tid;
            int crow = idx >> 3, ch = (idx & 7) << 3;
            u32x4 v = *(const u32x4*)(hTB + ((size_t)(c0 + crow) << 10) + j0 + ch);
            *(u32x4*)&Bl[crow][ch] = v;
        }
        __syncthreads();
#pragma unroll
        for (int kk = 0; kk < 2; ++kk) {
            bf16x8 av[4], bvf[2];
#pragma unroll
            for (int mi = 0; mi < 4; ++mi)
                av[mi] = *(const bf16x8*)&Al[wm * 64 + mi * 16 + lr][kk * 32 + lg * 8];
#pragma unroll
            for (int ni = 0; ni < 2; ++ni)
                bvf[ni] = *(const bf16x8*)&Bl[wn * 32 + ni * 16 + lr][kk * 32 + lg * 8];
#pragma unroll
            for (int mi = 0; mi < 4; ++mi)
#pragma unroll
                for (int ni = 0; ni < 2; ++ni)
                    acc[mi][ni] = __builtin_amdgcn_mfma_f32_16x16x32_bf16(
                        av[mi], bvf[ni], acc[mi][ni], 0, 0, 0);
        }
    }
    // epilogue: val = d_i * G + bias
#pragma unroll
    for (int mi = 0; mi < 4; ++mi) {
#pragma unroll
        for (int ni = 0; ni < 2; ++ni) {
            int cg = c0 + wn * 32 + ni * 16 + lr;
            float bias = (cg < 128) ? bq[cg] : (cg < 256 ? bk[cg - 128] : bv[cg - 256]);
#pragma unroll
            for (int r = 0; r < 4; ++r) {
                int gi = i0 + wm * 64 + mi * 16 + lg * 4 + r;
                float dv = dvec[(b << 10) + gi];
                float val = dv * acc[mi][ni][r] + bias;
                if (cg < 256) {
                    size_t base = (((size_t)b << 10) + gi) * 256 + cg;
                    unsigned short hi = f2bf(val);
                    QKhi[base] = hi;
                    QKlo[base] = f2bf(val - bf2f(hi));
                } else {
                    outV[(((size_t)b << 10) + gi) * 64 + (cg - 256)] = val;
                }
            }
        }
    }
}

// ---------------- kernel D: A = sym(mean_h tanh(Q_h K_h^T / 8)) ----------------
__global__ __launch_bounds__(256) void k_attn(const unsigned short* __restrict__ QKhi,
                                              const unsigned short* __restrict__ QKlo,
                                              float* __restrict__ Aout) {
    __shared__ float Sh[4][2][32][33];
    __shared__ float Asym[32][33];
    int bid = blockIdx.x;
    int xcd = bid & 7, t2 = bid >> 3;
    int bg = t2 / 528, pr = t2 - bg * 528;
    int b  = (bg << 3) + xcd;
    int ti = 0;
    {   // triangular decode (uniform)
        int p = pr;
        while (p >= (32 - ti)) { p -= (32 - ti); ++ti; }
        pr = p;
    }
    int tj = ti + pr;
    bool diag = (ti == tj);
    int qi0 = ti << 5, qj0 = tj << 5;
    int tid = threadIdx.x;
    int w = tid >> 6, l = tid & 63;
    int lr = l & 15, lg = l >> 4, lk = lg << 3;
    const unsigned short* hiB = QKhi + ((size_t)b << 18);
    const unsigned short* loB = QKlo + ((size_t)b << 18);
    int qcol = (w << 5) + lk;         // Q cols [0,128)
    int kcol = 128 + (w << 5) + lk;   // K cols [128,256)

    // dir 0: S_IJ = Q_I . K_J^T  (hi/lo 3-term for ~f32 accuracy)
    {
        bf16x8 qh[2], ql[2], kh[2], kl[2];
#pragma unroll
        for (int m = 0; m < 2; ++m) {
            size_t off = ((size_t)(qi0 + (m << 4) + lr) << 8) + qcol;
            qh[m] = *(const bf16x8*)(hiB + off);
            ql[m] = *(const bf16x8*)(loB + off);
        }
#pragma unroll
        for (int n = 0; n < 2; ++n) {
            size_t off = ((size_t)(qj0 + (n << 4) + lr) << 8) + kcol;
            kh[n] = *(const bf16x8*)(hiB + off);
            kl[n] = *(const bf16x8*)(loB + off);
        }
#pragma unroll
        for (int m = 0; m < 2; ++m)
#pragma unroll
            for (int n = 0; n < 2; ++n) {
                f32x4 s = {0.f, 0.f, 0.f, 0.f};
                s = __builtin_amdgcn_mfma_f32_16x16x32_bf16(qh[m], kh[n], s, 0, 0, 0);
                s = __builtin_amdgcn_mfma_f32_16x16x32_bf16(qh[m], kl[n], s, 0, 0, 0);
                s = __builtin_amdgcn_mfma_f32_16x16x32_bf16(ql[m], kh[n], s, 0, 0, 0);
#pragma unroll
                for (int r = 0; r < 4; ++r)
                    Sh[w][0][(m << 4) + (lg << 2) + r][(n << 4) + lr] =
                        tanh_fast(s[r] * 0.125f);
            }
    }
    if (!diag) {  // dir 1: S_JI = Q_J . K_I^T
        bf16x8 qh[2], ql[2], kh[2], kl[2];
#pragma unroll
        for (int m = 0; m < 2; ++m) {
            size_t off = ((size_t)(qj0 + (m << 4) + lr) << 8) + qcol;
            qh[m] = *(const bf16x8*)(hiB + off);
            ql[m] = *(const bf16x8*)(loB + off);
        }
#pragma unroll
        for (int n = 0; n < 2; ++n) {
            size_t off = ((size_t)(qi0 + (n << 4) + lr) << 8) + kcol;
            kh[n] = *(const bf16x8*)(hiB + off);
            kl[n] = *(const bf16x8*)(loB + off);
        }
#pragma unroll
        for (int m = 0; m < 2; ++m)
#pragma unroll
            for (int n = 0; n < 2; ++n) {
                f32x4 s = {0.f, 0.f, 0.f, 0.f};
                s = __builtin_amdgcn_mfma_f32_16x16x32_bf16(qh[m], kh[n], s, 0, 0, 0);
                s = __builtin_amdgcn_mfma_f32_16x16x32_bf16(qh[m], kl[n], s, 0, 0, 0);
                s = __builtin_amdgcn_mfma_f32_16x16x32_bf16(ql[m], kh[n], s, 0, 0, 0);
#pragma unroll
                for (int r = 0; r < 4; ++r)
                    Sh[w][1][(m << 4) + (lg << 2) + r][(n << 4) + lr] =
                        tanh_fast(s[r] * 0.125f);
            }
    }
    __syncthreads();
    // reduce heads, symmetrize, write A[I,J]
    {
        int r = tid >> 3, c4 = (tid & 7) << 2;
        f32x4 v;
#pragma unroll
        for (int e = 0; e < 4; ++e) {
            int c = c4 + e;
            float tij = Sh[0][0][r][c] + Sh[1][0][r][c] + Sh[2][0][r][c] + Sh[3][0][r][c];
            float tji;
            if (diag) tji = Sh[0][0][c][r] + Sh[1][0][c][r] + Sh[2][0][c][r] + Sh[3][0][c][r];
            else      tji = Sh[0][1][c][r] + Sh[1][1][c][r] + Sh[2][1][c][r] + Sh[3][1][c][r];
            float a = 0.125f * (tij + tji);   // 0.25 head-mean * 0.5 symmetrize
            v[e] = a;
            Asym[r][c] = a;
        }
        *(f32x4*)(Aout + ((size_t)b << 20) + ((size_t)(qi0 + r) << 10) + qj0 + c4) = v;
    }
    if (!diag) {  // write A[J,I] = A[I,J]^T (coalesced via LDS transpose)
        __syncthreads();
        int rj = tid >> 3, ci4 = (tid & 7) << 2;
        f32x4 v;
#pragma unroll
        for (int e = 0; e < 4; ++e) v[e] = Asym[ci4 + e][rj];
        *(f32x4*)(Aout + ((size_t)b << 20) + ((size_t)(qj0 + rj) << 10) + qi0 + ci4) = v;
    }
}

extern "C" void kernel_launch(void* const* d_in, const int* in_sizes, int n_in,
                              void* d_out, int out_size, void* d_ws, size_t ws_size,
                              hipStream_t stream) {
    const float* x   = (const float*)d_in[0];
    const float* adj = (const float*)d_in[1];
    // d_in[2] = flags (unused by reference forward)
    const float* Wq = (const float*)d_in[3];
    const float* bq = (const float*)d_in[4];
    const float* Wk = (const float*)d_in[5];
    const float* bk = (const float*)d_in[6];
    const float* Wv = (const float*)d_in[7];
    const float* bv = (const float*)d_in[8];

    float* out  = (float*)d_out;
    float* outV = out;                 // [32,1024,64]
    float* Aout = out + 2097152;       // [32,1024,1024]

    char* ws = (char*)d_ws;
    float*          dvec = (float*)ws;                                  // 128 KiB
    unsigned short* hT   = (unsigned short*)(ws + 131072);              // 20 MiB
    unsigned short* QKhi = (unsigned short*)(ws + 131072 + 20971520);   // 16 MiB
    unsigned short* QKlo = (unsigned short*)(ws + 131072 + 20971520 + 16777216); // 16 MiB

    hipLaunchKernelGGL(k_deg,  dim3(8192),  dim3(256), 0, stream, adj, dvec);
    hipLaunchKernelGGL(k_xw,   dim3(512),   dim3(256), 0, stream, x, Wq, Wk, Wv, dvec, hT);
    hipLaunchKernelGGL(k_gcn,  dim3(1280),  dim3(256), 0, stream, adj, hT, dvec,
                       bq, bk, bv, QKhi, QKlo, outV);
    hipLaunchKernelGGL(k_attn, dim3(16896), dim3(256), 0, stream, QKhi, QKlo, Aout);
}

// Round 2
// 418.709 us; speedup vs baseline: 1.7081x; 1.7081x over previous
//
#include <hip/hip_runtime.h>
#include <stdint.h>

// Problem constants: B=32, N=1024, IN=64, ATTN=128, OUT=64, H=4, dh=32
typedef __attribute__((ext_vector_type(4))) float f32x4;
typedef __attribute__((ext_vector_type(4))) unsigned int u32x4;
typedef __attribute__((ext_vector_type(2))) unsigned int u32x2;
typedef __attribute__((ext_vector_type(8))) short bf16x8;

__device__ __forceinline__ unsigned short f2bf(float f) {
    union { float f; unsigned int u; } c; c.f = f;
    unsigned int u = c.u;
    unsigned int r = (u + 0x7FFFu + ((u >> 16) & 1u)) >> 16;  // RNE
    return (unsigned short)r;
}
__device__ __forceinline__ float bf2f(unsigned short h) {
    union { unsigned int u; float f; } c; c.u = ((unsigned int)h) << 16;
    return c.f;
}
// branch-free tanh: saturates correctly at +/-inf, no clamp needed
__device__ __forceinline__ float tanh_fast(float x) {
    float t = __expf(2.0f * x);
    return 1.0f - 2.0f * __builtin_amdgcn_rcpf(t + 1.0f);
}

// ---------------- kernel A: degrees d = rsqrt(max(rowsum(adj'),1)) -------------
__global__ __launch_bounds__(256) void k_deg(const float* __restrict__ adj,
                                             float* __restrict__ dvec) {
    int wid = threadIdx.x >> 6, l = threadIdx.x & 63;
    int row = blockIdx.x * 4 + wid;          // 0..32767
    int b = row >> 10, i = row & 1023;
    const float* rp = adj + ((size_t)b << 20) + ((size_t)i << 10);
    float s = 0.f;
#pragma unroll
    for (int it = 0; it < 4; ++it) {
        f32x4 v = *(const f32x4*)(rp + it * 256 + l * 4);
        s += v.x + v.y + v.z + v.w;
    }
#pragma unroll
    for (int m = 32; m >= 1; m >>= 1) s += __shfl_xor(s, m);
    if (l == 0) {
        float diag = rp[i];
        float S = s - diag + 1.0f;     // diagonal replaced by 1
        S = fmaxf(S, 1.0f);
        dvec[(b << 10) + i] = 1.0f / sqrtf(S);
    }
}

// ---------------- kernel B: xsT[b][c][j] = bf16(d_j * x[b][j][c]) --------------
__global__ __launch_bounds__(256) void k_xs(const float* __restrict__ x,
                                            const float* __restrict__ dvec,
                                            unsigned short* __restrict__ xsT) {
    __shared__ float Lt[64][65];
    int b = blockIdx.x >> 4, j0 = (blockIdx.x & 15) << 6;
    int tid = threadIdx.x;
    {
        int r = tid >> 2, cseg = (tid & 3) << 4;
        float dj = dvec[(b << 10) + j0 + r];
        const float* xr = x + (((size_t)((b << 10) + j0 + r)) << 6) + cseg;
#pragma unroll
        for (int q = 0; q < 4; ++q) {
            f32x4 v = *(const f32x4*)(xr + (q << 2));
#pragma unroll
            for (int e = 0; e < 4; ++e) Lt[r][cseg + (q << 2) + e] = v[e] * dj;
        }
    }
    __syncthreads();
    {
        int c = tid >> 2, js = (tid & 3) << 4;
        unsigned int pk[8];
#pragma unroll
        for (int e = 0; e < 8; ++e) {
            unsigned short lo16 = f2bf(Lt[js + 2 * e][c]);
            unsigned short hi16 = f2bf(Lt[js + 2 * e + 1][c]);
            pk[e] = (unsigned)lo16 | ((unsigned)hi16 << 16);
        }
        unsigned short* op = xsT + ((size_t)b << 16) + ((size_t)c << 10) + j0 + js;
        u32x4 w0 = {pk[0], pk[1], pk[2], pk[3]};
        u32x4 w1 = {pk[4], pk[5], pk[6], pk[7]};
        *(u32x4*)op = w0;
        *(u32x4*)(op + 8) = w1;
    }
}

// ---------------- kernel C: Mg[i][c] = d_i * sum_j adj'[i][j] * xs[j][c] -------
#define APAD 72   // LDS row stride (bf16 elems)
__global__ __launch_bounds__(256) void k_m(const float* __restrict__ adj,
                                           const unsigned short* __restrict__ xsT,
                                           const float* __restrict__ dvec,
                                           float* __restrict__ Mg) {
    __shared__ unsigned short Al[32][APAD];
    __shared__ unsigned short Bl[64][APAD];
    // XCD swizzle: batch b pinned to XCD b&7
    int bid = blockIdx.x;
    int xcd = bid & 7, t2 = bid >> 3;
    int bg = t2 >> 5, mt = t2 & 31;
    int b = (bg << 3) + xcd;
    int i0 = mt << 5;
    int tid = threadIdx.x;
    int wid = tid >> 6, l = tid & 63;
    int wm = wid >> 1, wn = wid & 1;
    int lr = l & 15, lg = l >> 4;

    f32x4 acc[2];
    acc[0] = (f32x4){0.f, 0.f, 0.f, 0.f};
    acc[1] = (f32x4){0.f, 0.f, 0.f, 0.f};

    const float* adjB = adj + ((size_t)b << 20);
    const unsigned short* xsB = xsT + ((size_t)b << 16);
    int ar0 = tid >> 4;            // 0..15
    int ac4 = (tid & 15) << 2;     // 0..60

    for (int kt = 0; kt < 16; ++kt) {
        int j0 = kt << 6;
        __syncthreads();
        // stage A: adj[i0..+31][j0..+63] f32 -> bf16, diag patch
#pragma unroll
        for (int rr = 0; rr < 2; ++rr) {
            int row = ar0 + (rr << 4);
            int gi  = i0 + row;
            f32x4 v = *(const f32x4*)(adjB + ((size_t)gi << 10) + j0 + ac4);
            int gj = j0 + ac4;
            if (gj + 0 == gi) v.x = 1.0f;
            if (gj + 1 == gi) v.y = 1.0f;
            if (gj + 2 == gi) v.z = 1.0f;
            if (gj + 3 == gi) v.w = 1.0f;
            u32x2 pk;
            pk.x = (unsigned)f2bf(v.x) | ((unsigned)f2bf(v.y) << 16);
            pk.y = (unsigned)f2bf(v.z) | ((unsigned)f2bf(v.w) << 16);
            *(u32x2*)&Al[row][ac4] = pk;
        }
        // stage B: xsT rows 0..63 (c), cols j0..+63 (already bf16)
#pragma unroll
        for (int rep = 0; rep < 2; ++rep) {
            int idx = (rep << 8) + tid;
            int crow = idx >> 3, ch = (idx & 7) << 3;
            u32x4 v = *(const u32x4*)(xsB + ((size_t)crow << 10) + j0 + ch);
            *(u32x4*)&Bl[crow][ch] = v;
        }
        __syncthreads();
#pragma unroll
        for (int kk = 0; kk < 2; ++kk) {
            bf16x8 av = *(const bf16x8*)&Al[wm * 16 + lr][kk * 32 + lg * 8];
            bf16x8 b0 = *(const bf16x8*)&Bl[wn * 32 + lr][kk * 32 + lg * 8];
            bf16x8 b1 = *(const bf16x8*)&Bl[wn * 32 + 16 + lr][kk * 32 + lg * 8];
            acc[0] = __builtin_amdgcn_mfma_f32_16x16x32_bf16(av, b0, acc[0], 0, 0, 0);
            acc[1] = __builtin_amdgcn_mfma_f32_16x16x32_bf16(av, b1, acc[1], 0, 0, 0);
        }
    }
    // epilogue: Mg = d_i * acc
#pragma unroll
    for (int r = 0; r < 4; ++r) {
        int gi = i0 + wm * 16 + lg * 4 + r;
        float dv = dvec[(b << 10) + gi];
#pragma unroll
        for (int ni = 0; ni < 2; ++ni) {
            int cg = wn * 32 + ni * 16 + lr;
            Mg[(((size_t)((b << 10) + gi)) << 6) + cg] = dv * acc[ni][r];
        }
    }
}

// ---------------- kernel D: [QKV] = Mg @ W + bias (hi/lo MFMA, ~f32 accurate) --
#define QPAD 72
__global__ __launch_bounds__(256) void k_qkv(const float* __restrict__ Mg,
                                             const float* __restrict__ Wq,
                                             const float* __restrict__ Wk,
                                             const float* __restrict__ Wv,
                                             const float* __restrict__ bq,
                                             const float* __restrict__ bk,
                                             const float* __restrict__ bv,
                                             unsigned short* __restrict__ QKhi,
                                             unsigned short* __restrict__ QKlo,
                                             float* __restrict__ outV) {
    __shared__ unsigned short WThi[320][QPAD];
    __shared__ unsigned short WTlo[320][QPAD];
    __shared__ float biasl[320];
    int tid = threadIdx.x;
    // stage W^T hi/lo into LDS (coalesced global reads)
#pragma unroll 1
    for (int it = 0; it < 32; ++it) {
        int idx = (it << 8) + tid;
        int k = idx >> 7, c = idx & 127;
        float w = Wq[idx];
        unsigned short h = f2bf(w);
        WThi[c][k] = h; WTlo[c][k] = f2bf(w - bf2f(h));
    }
#pragma unroll 1
    for (int it = 0; it < 32; ++it) {
        int idx = (it << 8) + tid;
        int k = idx >> 7, c = idx & 127;
        float w = Wk[idx];
        unsigned short h = f2bf(w);
        WThi[128 + c][k] = h; WTlo[128 + c][k] = f2bf(w - bf2f(h));
    }
#pragma unroll 1
    for (int it = 0; it < 16; ++it) {
        int idx = (it << 8) + tid;
        int k = idx >> 6, c = idx & 63;
        float w = Wv[idx];
        unsigned short h = f2bf(w);
        WThi[256 + c][k] = h; WTlo[256 + c][k] = f2bf(w - bf2f(h));
    }
    for (int e = tid; e < 320; e += 256)
        biasl[e] = (e < 128) ? bq[e] : ((e < 256) ? bk[e - 128] : bv[e - 256]);

    // A-frags (Mg rows) straight from global, split hi/lo
    int wid = tid >> 6, l = tid & 63, lr = l & 15, lg = l >> 4;
    int gr0 = (blockIdx.x << 6) + (wid << 4);
    const float* mrow = Mg + (((size_t)(gr0 + lr)) << 6);
    bf16x8 ahi[2], alo[2];
#pragma unroll
    for (int kk = 0; kk < 2; ++kk) {
        f32x4 v0 = *(const f32x4*)(mrow + kk * 32 + lg * 8);
        f32x4 v1 = *(const f32x4*)(mrow + kk * 32 + lg * 8 + 4);
#pragma unroll
        for (int e = 0; e < 8; ++e) {
            float f = (e < 4) ? v0[e] : v1[e - 4];
            unsigned short h = f2bf(f);
            ahi[kk][e] = (short)h;
            alo[kk][e] = (short)f2bf(f - bf2f(h));
        }
    }
    __syncthreads();

    f32x4 acc[20];
#pragma unroll
    for (int n = 0; n < 20; ++n) acc[n] = (f32x4){0.f, 0.f, 0.f, 0.f};
#pragma unroll
    for (int n = 0; n < 20; ++n) {
#pragma unroll
        for (int kk = 0; kk < 2; ++kk) {
            bf16x8 bh = *(const bf16x8*)&WThi[n * 16 + lr][kk * 32 + lg * 8];
            bf16x8 bl = *(const bf16x8*)&WTlo[n * 16 + lr][kk * 32 + lg * 8];
            acc[n] = __builtin_amdgcn_mfma_f32_16x16x32_bf16(ahi[kk], bh, acc[n], 0, 0, 0);
            acc[n] = __builtin_amdgcn_mfma_f32_16x16x32_bf16(ahi[kk], bl, acc[n], 0, 0, 0);
            acc[n] = __builtin_amdgcn_mfma_f32_16x16x32_bf16(alo[kk], bh, acc[n], 0, 0, 0);
        }
    }
    // epilogue
#pragma unroll
    for (int n = 0; n < 20; ++n) {
        int c = n * 16 + lr;
        float bias = biasl[c];
#pragma unroll
        for (int r = 0; r < 4; ++r) {
            int gr = gr0 + lg * 4 + r;
            float val = acc[n][r] + bias;
            if (n < 16) {   // c < 256 uniform per n
                size_t base = ((size_t)gr << 8) + c;
                unsigned short h = f2bf(val);
                QKhi[base] = h;
                QKlo[base] = f2bf(val - bf2f(h));
            } else {
                outV[((size_t)gr << 6) + (c - 256)] = val;
            }
        }
    }
}

// ---------------- kernel E: A = sym(mean_h tanh(Q_h K_h^T / 8)) ----------------
__global__ __launch_bounds__(256) void k_attn(const unsigned short* __restrict__ QKhi,
                                              const unsigned short* __restrict__ QKlo,
                                              float* __restrict__ Aout) {
    __shared__ float Sh[4][2][32][33];
    __shared__ float Asym[32][33];
    int bid = blockIdx.x;
    int xcd = bid & 7, t2 = bid >> 3;
    int bg = t2 / 528, pr = t2 - bg * 528;
    int b  = (bg << 3) + xcd;
    int ti = 0;
    {   // triangular decode (uniform)
        int p = pr;
        while (p >= (32 - ti)) { p -= (32 - ti); ++ti; }
        pr = p;
    }
    int tj = ti + pr;
    bool diag = (ti == tj);
    int qi0 = ti << 5, qj0 = tj << 5;
    int tid = threadIdx.x;
    int w = tid >> 6, l = tid & 63;
    int lr = l & 15, lg = l >> 4, lk = lg << 3;
    const unsigned short* hiB = QKhi + ((size_t)b << 18);
    const unsigned short* loB = QKlo + ((size_t)b << 18);
    int qcol = (w << 5) + lk;         // Q cols [0,128)
    int kcol = 128 + (w << 5) + lk;   // K cols [128,256)

    // dir 0: S_IJ = Q_I . K_J^T  (hi/lo 3-term for ~f32 accuracy)
    {
        bf16x8 qh[2], ql[2], kh[2], kl[2];
#pragma unroll
        for (int m = 0; m < 2; ++m) {
            size_t off = ((size_t)(qi0 + (m << 4) + lr) << 8) + qcol;
            qh[m] = *(const bf16x8*)(hiB + off);
            ql[m] = *(const bf16x8*)(loB + off);
        }
#pragma unroll
        for (int n = 0; n < 2; ++n) {
            size_t off = ((size_t)(qj0 + (n << 4) + lr) << 8) + kcol;
            kh[n] = *(const bf16x8*)(hiB + off);
            kl[n] = *(const bf16x8*)(loB + off);
        }
#pragma unroll
        for (int m = 0; m < 2; ++m)
#pragma unroll
            for (int n = 0; n < 2; ++n) {
                f32x4 s = {0.f, 0.f, 0.f, 0.f};
                s = __builtin_amdgcn_mfma_f32_16x16x32_bf16(qh[m], kh[n], s, 0, 0, 0);
                s = __builtin_amdgcn_mfma_f32_16x16x32_bf16(qh[m], kl[n], s, 0, 0, 0);
                s = __builtin_amdgcn_mfma_f32_16x16x32_bf16(ql[m], kh[n], s, 0, 0, 0);
#pragma unroll
                for (int r = 0; r < 4; ++r)
                    Sh[w][0][(m << 4) + (lg << 2) + r][(n << 4) + lr] =
                        tanh_fast(s[r] * 0.125f);
            }
    }
    if (!diag) {  // dir 1: S_JI = Q_J . K_I^T
        bf16x8 qh[2], ql[2], kh[2], kl[2];
#pragma unroll
        for (int m = 0; m < 2; ++m) {
            size_t off = ((size_t)(qj0 + (m << 4) + lr) << 8) + qcol;
            qh[m] = *(const bf16x8*)(hiB + off);
            ql[m] = *(const bf16x8*)(loB + off);
        }
#pragma unroll
        for (int n = 0; n < 2; ++n) {
            size_t off = ((size_t)(qi0 + (n << 4) + lr) << 8) + kcol;
            kh[n] = *(const bf16x8*)(hiB + off);
            kl[n] = *(const bf16x8*)(loB + off);
        }
#pragma unroll
        for (int m = 0; m < 2; ++m)
#pragma unroll
            for (int n = 0; n < 2; ++n) {
                f32x4 s = {0.f, 0.f, 0.f, 0.f};
                s = __builtin_amdgcn_mfma_f32_16x16x32_bf16(qh[m], kh[n], s, 0, 0, 0);
                s = __builtin_amdgcn_mfma_f32_16x16x32_bf16(qh[m], kl[n], s, 0, 0, 0);
                s = __builtin_amdgcn_mfma_f32_16x16x32_bf16(ql[m], kh[n], s, 0, 0, 0);
#pragma unroll
                for (int r = 0; r < 4; ++r)
                    Sh[w][1][(m << 4) + (lg << 2) + r][(n << 4) + lr] =
                        tanh_fast(s[r] * 0.125f);
            }
    }
    __syncthreads();
    // reduce heads, symmetrize, write A[I,J]
    {
        int r = tid >> 3, c4 = (tid & 7) << 2;
        f32x4 v;
#pragma unroll
        for (int e = 0; e < 4; ++e) {
            int c = c4 + e;
            float tij = Sh[0][0][r][c] + Sh[1][0][r][c] + Sh[2][0][r][c] + Sh[3][0][r][c];
            float tji;
            if (diag) tji = Sh[0][0][c][r] + Sh[1][0][c][r] + Sh[2][0][c][r] + Sh[3][0][c][r];
            else      tji = Sh[0][1][c][r] + Sh[1][1][c][r] + Sh[2][1][c][r] + Sh[3][1][c][r];
            float a = 0.125f * (tij + tji);   // 0.25 head-mean * 0.5 symmetrize
            v[e] = a;
            Asym[r][c] = a;
        }
        *(f32x4*)(Aout + ((size_t)b << 20) + ((size_t)(qi0 + r) << 10) + qj0 + c4) = v;
    }
    if (!diag) {  // write A[J,I] = A[I,J]^T (coalesced via LDS transpose)
        __syncthreads();
        int rj = tid >> 3, ci4 = (tid & 7) << 2;
        f32x4 v;
#pragma unroll
        for (int e = 0; e < 4; ++e) v[e] = Asym[ci4 + e][rj];
        *(f32x4*)(Aout + ((size_t)b << 20) + ((size_t)(qj0 + rj) << 10) + qi0 + ci4) = v;
    }
}

extern "C" void kernel_launch(void* const* d_in, const int* in_sizes, int n_in,
                              void* d_out, int out_size, void* d_ws, size_t ws_size,
                              hipStream_t stream) {
    const float* x   = (const float*)d_in[0];
    const float* adj = (const float*)d_in[1];
    // d_in[2] = flags (unused by reference forward)
    const float* Wq = (const float*)d_in[3];
    const float* bq = (const float*)d_in[4];
    const float* Wk = (const float*)d_in[5];
    const float* bk = (const float*)d_in[6];
    const float* Wv = (const float*)d_in[7];
    const float* bv = (const float*)d_in[8];

    float* out  = (float*)d_out;
    float* outV = out;                 // [32,1024,64]
    float* Aout = out + 2097152;       // [32,1024,1024]

    char* ws = (char*)d_ws;
    float*          dvec = (float*)ws;                                   // 128 KiB
    unsigned short* xsT  = (unsigned short*)(ws + 131072);               // 4 MiB
    float*          Mg   = (float*)(ws + 131072 + 4194304);              // 8 MiB
    unsigned short* QKhi = (unsigned short*)(ws + 131072 + 4194304 + 8388608);            // 16 MiB
    unsigned short* QKlo = (unsigned short*)(ws + 131072 + 4194304 + 8388608 + 16777216); // 16 MiB

    hipLaunchKernelGGL(k_deg,  dim3(8192),  dim3(256), 0, stream, adj, dvec);
    hipLaunchKernelGGL(k_xs,   dim3(512),   dim3(256), 0, stream, x, dvec, xsT);
    hipLaunchKernelGGL(k_m,    dim3(1024),  dim3(256), 0, stream, adj, xsT, dvec, Mg);
    hipLaunchKernelGGL(k_qkv,  dim3(512),   dim3(256), 0, stream, Mg, Wq, Wk, Wv,
                       bq, bk, bv, QKhi, QKlo, outV);
    hipLaunchKernelGGL(k_attn, dim3(16896), dim3(256), 0, stream, QKhi, QKlo, Aout);
}